// Round 3
// baseline (544.120 us; speedup 1.0000x reference)
//
#include <hip/hip_runtime.h>
#include <hip/hip_fp16.h>

// Problem constants (B=2, P=64, N=256, C=512, H=8, D=64)
#define BP   128
#define NTOK 256
#define CDIM 512
#define ROWS 32768   // BP*NTOK
#define NH   8
#define DH   64

typedef _Float16 h2_t __attribute__((ext_vector_type(2)));
typedef _Float16 h4_t __attribute__((ext_vector_type(4)));
typedef _Float16 h8_t __attribute__((ext_vector_type(8)));
typedef float    f4_t __attribute__((ext_vector_type(4)));
typedef unsigned int u2v __attribute__((ext_vector_type(2)));

// pack two f32 -> two fp16 in one u32 (v_cvt_pkrtz_f16_f32)
__device__ __forceinline__ unsigned pkrtz(float a, float b) {
    return __builtin_bit_cast(unsigned, __builtin_amdgcn_cvt_pkrtz(a, b));
}

// async global->LDS, 16B per lane. LDS dest = wave-uniform base + lane*16.
__device__ __forceinline__ void async16(const void* gptr, void* lptr) {
    __builtin_amdgcn_global_load_lds(
        (const __attribute__((address_space(1))) unsigned int*)gptr,
        (__attribute__((address_space(3))) unsigned int*)lptr, 16, 0, 0);
}

// permlane32_swap: swaps lanes 32-63 of a with lanes 0-31 of b.
__device__ __forceinline__ u2v pl32swap(unsigned a, unsigned b) {
#if __has_builtin(__builtin_amdgcn_permlane32_swap)
    return __builtin_amdgcn_permlane32_swap(a, b, false, false);
#else
    const bool hi = (threadIdx.x & 32) != 0;
    unsigned sa = (unsigned)__shfl_xor((int)a, 32);
    unsigned sb = (unsigned)__shfl_xor((int)b, 32);
    u2v r; r[0] = hi ? sb : a; r[1] = hi ? b : sa; return r;
#endif
}

// permlane16_swap: swaps odd 16-lane rows of a with even rows of b.
__device__ __forceinline__ u2v pl16swap(unsigned a, unsigned b) {
#if __has_builtin(__builtin_amdgcn_permlane16_swap)
    return __builtin_amdgcn_permlane16_swap(a, b, false, false);
#else
    const bool odd = (threadIdx.x & 16) != 0;
    unsigned sa = (unsigned)__shfl_xor((int)a, 16);
    unsigned sb = (unsigned)__shfl_xor((int)b, 16);
    u2v r; r[0] = odd ? sb : a; r[1] = odd ? b : sa; return r;
#endif
}

// ---------------------------------------------------------------------------
// LayerNorm + cast to fp16. One wave per row of 512.
// ---------------------------------------------------------------------------
__global__ __launch_bounds__(256) void ln_cast(const float* __restrict__ x,
                                               const float* __restrict__ g,
                                               const float* __restrict__ b,
                                               _Float16* __restrict__ y) {
    const int wave = threadIdx.x >> 6, lane = threadIdx.x & 63;
    const size_t row = (size_t)blockIdx.x * 4 + wave;
    const float4* xr = (const float4*)(x + row * CDIM);
    float4 a0 = xr[2 * lane], a1 = xr[2 * lane + 1];
    float s  = a0.x + a0.y + a0.z + a0.w + a1.x + a1.y + a1.z + a1.w;
    float ss = a0.x * a0.x + a0.y * a0.y + a0.z * a0.z + a0.w * a0.w +
               a1.x * a1.x + a1.y * a1.y + a1.z * a1.z + a1.w * a1.w;
#pragma unroll
    for (int off = 32; off; off >>= 1) {
        s  += __shfl_xor(s, off);
        ss += __shfl_xor(ss, off);
    }
    const float mu = s * (1.f / 512.f);
    const float rs = rsqrtf(ss * (1.f / 512.f) - mu * mu + 1e-5f);
    const float4* gp = (const float4*)g;
    const float4* bpp = (const float4*)b;
    float4 g0 = gp[2 * lane], g1 = gp[2 * lane + 1];
    float4 b0 = bpp[2 * lane], b1 = bpp[2 * lane + 1];
    h8_t o;
    o[0] = (_Float16)((a0.x - mu) * rs * g0.x + b0.x);
    o[1] = (_Float16)((a0.y - mu) * rs * g0.y + b0.y);
    o[2] = (_Float16)((a0.z - mu) * rs * g0.z + b0.z);
    o[3] = (_Float16)((a0.w - mu) * rs * g0.w + b0.w);
    o[4] = (_Float16)((a1.x - mu) * rs * g1.x + b1.x);
    o[5] = (_Float16)((a1.y - mu) * rs * g1.y + b1.y);
    o[6] = (_Float16)((a1.z - mu) * rs * g1.z + b1.z);
    o[7] = (_Float16)((a1.w - mu) * rs * g1.w + b1.w);
    ((h8_t*)(y + row * CDIM))[lane] = o;
}

// ---------------------------------------------------------------------------
// Cast the 4 weight matrices (512x512 f32) to fp16. Wq gets *0.125 folded in.
// ---------------------------------------------------------------------------
__global__ __launch_bounds__(256) void cast_w4(const float* __restrict__ w0,
                                               const float* __restrict__ w1,
                                               const float* __restrict__ w2,
                                               const float* __restrict__ w3,
                                               _Float16* __restrict__ o) {
    const float* srcs[4] = {w0, w1, w2, w3};
    const float* w = srcs[blockIdx.y];
    const float scale = (blockIdx.y == 0) ? 0.125f : 1.0f;
    _Float16* dst = o + (size_t)blockIdx.y * (CDIM * CDIM);
    const int idx = blockIdx.x * 256 + threadIdx.x;  // 65536 float4 chunks
    float4 v = ((const float4*)w)[idx];
    h4_t ov = {(_Float16)(v.x * scale), (_Float16)(v.y * scale),
               (_Float16)(v.z * scale), (_Float16)(v.w * scale)};
    ((h4_t*)dst)[idx] = ov;
}

// ---------------------------------------------------------------------------
// GEMM (m97 structure): C[M=32768, 512] = A[32768,512] @ B^T.
// 1D grid (1024 blocks), XCD-chunked swizzle: xcd = bid&7 owns row-tiles
// [xcd*32, +32), iterating the 4 column tiles fastest so the same A row-panel
// hits that XCD's L2 4x (A fetched once from HBM instead of 4x).
// ---------------------------------------------------------------------------
template <int MODE>
__global__ __launch_bounds__(256) void gemm_bt(const _Float16* __restrict__ A,
                                               const _Float16* __restrict__ Bw,
                                               _Float16* __restrict__ Ch,
                                               float* __restrict__ Cf,
                                               const float* __restrict__ bias) {
    constexpr int K = CDIM;
    __shared__ __align__(16) _Float16 As[128 * 64];
    __shared__ __align__(16) _Float16 Bs[128 * 64];
    const int t = threadIdx.x;
    const int wave = t >> 6, lane = t & 63;
    const int wm = wave & 1, wn = wave >> 1;

    const int bid = blockIdx.x;          // 0..1023
    const int xcd = bid & 7, idx = bid >> 3;          // 128 per XCD
    const size_t rowBase = (size_t)(xcd * 32 + (idx >> 2)) * 128;
    const int colBase = (idx & 3) * 128;

    f4_t acc[4][4] = {};

    const int srow = t >> 3;
    const int scol = (t & 7) * 8;
    const _Float16* Ap = A + (rowBase + srow) * K + scol;
    const _Float16* Bp = Bw + ((size_t)colBase + srow) * K + scol;
    char* AsB = (char*)As + wave * 1024;
    char* BsB = (char*)Bs + wave * 1024;

    for (int k0 = 0; k0 < K; k0 += 64) {
#pragma unroll
        for (int c = 0; c < 4; ++c) {
            async16(Ap + (size_t)(32 * c) * K + k0, AsB + c * 4096);
            async16(Bp + (size_t)(32 * c) * K + k0, BsB + c * 4096);
        }
        __syncthreads();
#pragma unroll
        for (int kk = 0; kk < 64; kk += 32) {
            h8_t af[4], bf[4];
#pragma unroll
            for (int i = 0; i < 4; ++i)
                af[i] = *(const h8_t*)(As + (wm * 64 + i * 16 + (lane & 15)) * 64 +
                                       kk + (lane >> 4) * 8);
#pragma unroll
            for (int j = 0; j < 4; ++j)
                bf[j] = *(const h8_t*)(Bs + (wn * 64 + j * 16 + (lane & 15)) * 64 +
                                       kk + (lane >> 4) * 8);
#pragma unroll
            for (int i = 0; i < 4; ++i)
#pragma unroll
                for (int j = 0; j < 4; ++j)
                    acc[i][j] = __builtin_amdgcn_mfma_f32_16x16x32_f16(
                        af[i], bf[j], acc[i][j], 0, 0, 0);
        }
        __syncthreads();
    }
#pragma unroll
    for (int i = 0; i < 4; ++i) {
        const size_t growb = rowBase + wm * 64 + i * 16 + ((lane >> 4) * 4);
#pragma unroll
        for (int j = 0; j < 4; ++j) {
            const int gcol = colBase + wn * 64 + j * 16 + (lane & 15);
            if (MODE == 2) {
                const int bp = (int)(growb >> 8), tok = (int)(growb & 255);
                const int hh = gcol >> 6, dd = gcol & 63;
                h4_t w = {(_Float16)acc[i][j][0], (_Float16)acc[i][j][1],
                          (_Float16)acc[i][j][2], (_Float16)acc[i][j][3]};
                *(h4_t*)(Ch + ((size_t)(bp * NH + hh) * DH + dd) * NTOK + tok) = w;
            } else {
#pragma unroll
                for (int r = 0; r < 4; ++r) {
                    const size_t idx2 = (growb + r) * CDIM + gcol;
                    if (MODE == 0)
                        Ch[idx2] = (_Float16)acc[i][j][r];
                    else
                        Cf[idx2] = acc[i][j][r] + bias[gcol];
                }
            }
        }
    }
}

// ---------------------------------------------------------------------------
// MFMA flash attention, v3: double-buffered 2-phase pipeline (T3+T4 minimum).
// 1D grid 2048, XCD swizzle: xcd = bid&7 = bp&7 so all 16 blocks sharing
// mask[bp] run on one XCD (mask fetched once; pos[h] 2MB stays L2-resident).
// Per block: wave w owns 32 queries. Per chunk c (64 keys):
//   issue global_load_lds for chunk c+1 into buf^1, then
//   s_waitcnt vmcnt(4) (cur chunk's 4 staging ops are the oldest outstanding
//   -> counted wait can only over-wait) + raw s_barrier, compute from buf,
//   raw s_barrier (readers done before next iter re-stages this buf).
// K/V LDS 16B-slot XOR-swizzled via pre-swizzled global source (involution).
// S^T = K Q^T; P -> B-fragment in-register (cvt_pkrtz + permlane swaps);
// O^T += V^T P^T; l reduced once at end. LDS 32 KB, VGPR ~64.
// ---------------------------------------------------------------------------
__global__ __launch_bounds__(256, 4) void attn_mfma(const _Float16* __restrict__ Q,
                                                    const _Float16* __restrict__ K,
                                                    const _Float16* __restrict__ VT,
                                                    const float* __restrict__ mask,
                                                    const float* __restrict__ pos,
                                                    _Float16* __restrict__ O) {
    const int bid = blockIdx.x;                   // 0..2047
    const int xcd = bid & 7, idx = bid >> 3;      // 256 per XCD
    const int bp = xcd + 8 * (idx >> 4);          // same-XCD blocks share bp
    const int sub = idx & 15;
    const int h = sub & 7, qh = sub >> 3;

    const int t = threadIdx.x;
    const int wave = t >> 6, lane = t & 63;
    const int g = lane >> 4, li = lane & 15;

    __shared__ __align__(16) _Float16 Ks[2][64 * 64];   // [j][d], slot-swizzled
    __shared__ __align__(16) _Float16 VTs[2][64 * 64];  // [d][j], slot-swizzled

    const int i0 = qh * 128 + wave * 32;

    // Q B-fragments, resident: qf[it][x]: rows i0+it*16+li, k = x*32+g*8..+8
    h8_t qf[2][2];
#pragma unroll
    for (int it = 0; it < 2; ++it)
#pragma unroll
        for (int x = 0; x < 2; ++x)
            qf[it][x] = *(const h8_t*)(Q +
                (size_t)(bp * NTOK + i0 + it * 16 + li) * CDIM +
                h * DH + x * 32 + g * 8);

    // staging: wave w covers LDS bytes [w*2048, +2048) in 2 calls of 1KB.
    // LDS byte = w*2048 + call*1024 + lane*16 -> row = w*16+call*8+(lane>>3),
    // slot = lane&7; source slot = (lane&7) ^ (row&7).
    const int srow = wave * 16 + (lane >> 3);
    const int sslot = (lane & 7) ^ ((lane >> 3) & 7);
    const _Float16* kSrc = K + ((size_t)(bp * NTOK) + srow) * CDIM + h * DH + sslot * 8;
    const _Float16* vSrc = VT + ((size_t)((bp * NH + h) * DH) + srow) * NTOK + sslot * 8;
    char* KsB[2] = {(char*)Ks[0] + wave * 2048, (char*)Ks[1] + wave * 2048};
    char* VsB[2] = {(char*)VTs[0] + wave * 2048, (char*)VTs[1] + wave * 2048};

    // swizzled read column offsets (fp16 elems): rows jt*16+li -> row&7 = li&7
    const int sw = li & 7;
    const int cx0 = (g ^ sw) * 8;        // x=0: slot g
    const int cx1 = ((4 + g) ^ sw) * 8;  // x=1: slot 4+g

    const float* mrow0 = mask + (size_t)bp * (NTOK * NTOK) + (size_t)(i0 + li) * NTOK + g * 4;
    const float* prow0 = pos + (size_t)h * (NTOK * NTOK) + (size_t)(i0 + li) * NTOK + g * 4;

    f4_t o[4][2] = {};   // O^T tiles [dt][it]
    float lp[2] = {0.f, 0.f};

    // prologue: stage chunk 0 into buf 0
    async16(kSrc, KsB[0]);
    async16(kSrc + 8 * CDIM, KsB[0] + 1024);
    async16(vSrc, VsB[0]);
    async16(vSrc + 8 * NTOK, VsB[0] + 1024);

#pragma unroll
    for (int c = 0; c < 4; ++c) {
        const int cur = c & 1;
        if (c < 3) {
            const int nb = cur ^ 1;
            async16(kSrc + (size_t)(c + 1) * 64 * CDIM, KsB[nb]);
            async16(kSrc + (size_t)(c + 1) * 64 * CDIM + 8 * CDIM, KsB[nb] + 1024);
            async16(vSrc + (c + 1) * 64, VsB[nb]);
            async16(vSrc + (c + 1) * 64 + 8 * NTOK, VsB[nb] + 1024);
            asm volatile("s_waitcnt vmcnt(4)" ::: "memory");
        } else {
            asm volatile("s_waitcnt vmcnt(0)" ::: "memory");
        }
        __builtin_amdgcn_s_barrier();
        __builtin_amdgcn_sched_barrier(0);

        const _Float16* Kc = Ks[cur];
        const _Float16* Vc = VTs[cur];

        // S^T = K Q^T
        f4_t s[4][2] = {};
#pragma unroll
        for (int x = 0; x < 2; ++x) {
            const int cc = x ? cx1 : cx0;
            h8_t kf[4];
#pragma unroll
            for (int jt = 0; jt < 4; ++jt)
                kf[jt] = *(const h8_t*)(Kc + (jt * 16 + li) * 64 + cc);
#pragma unroll
            for (int jt = 0; jt < 4; ++jt)
#pragma unroll
                for (int it = 0; it < 2; ++it)
                    s[jt][it] = __builtin_amdgcn_mfma_f32_16x16x32_f16(
                        kf[jt], qf[it][x], s[jt][it], 0, 0, 0);
        }

        // transform: p = exp(mask*(s + pos)); accumulate l; build B-fragments
        // in-register (cvt_pkrtz + permlane swaps), no LDS round-trip.
        h8_t pf[2][2];
#pragma unroll
        for (int it = 0; it < 2; ++it) {
            const float* mr = mrow0 + it * (16 * NTOK) + c * 64;
            const float* pr = prow0 + it * (16 * NTOK) + c * 64;
            unsigned pk[4][2];
#pragma unroll
            for (int jt = 0; jt < 4; ++jt) {
                float4 mm = *(const float4*)(mr + jt * 16);
                float4 pp = *(const float4*)(pr + jt * 16);
                float e0 = __expf((s[jt][it][0] + pp.x) * mm.x);
                float e1 = __expf((s[jt][it][1] + pp.y) * mm.y);
                float e2 = __expf((s[jt][it][2] + pp.z) * mm.z);
                float e3 = __expf((s[jt][it][3] + pp.w) * mm.w);
                lp[it] += (e0 + e1) + (e2 + e3);
                pk[jt][0] = pkrtz(e0, e1);  // rows (4g, 4g+1)
                pk[jt][1] = pkrtz(e2, e3);  // rows (4g+2, 4g+3)
            }
#pragma unroll
            for (int x = 0; x < 2; ++x) {
                u2v r0 = pl32swap(pk[2 * x][0], pk[2 * x + 1][0]);
                u2v r1 = pl32swap(pk[2 * x][1], pk[2 * x + 1][1]);
                u2v q0 = pl16swap(r0[0], r0[1]);
                u2v q1 = pl16swap(r1[0], r1[1]);
                union { unsigned u[4]; h8_t v; } u;
                u.u[0] = q0[0]; u.u[1] = q1[0]; u.u[2] = q0[1]; u.u[3] = q1[1];
                pf[it][x] = u.v;
            }
        }

        // O^T += V^T P^T
#pragma unroll
        for (int x = 0; x < 2; ++x) {
            const int cc = x ? cx1 : cx0;
            h8_t vf[4];
#pragma unroll
            for (int dt = 0; dt < 4; ++dt)
                vf[dt] = *(const h8_t*)(Vc + (dt * 16 + li) * 64 + cc);
#pragma unroll
            for (int dt = 0; dt < 4; ++dt)
#pragma unroll
                for (int it = 0; it < 2; ++it)
                    o[dt][it] = __builtin_amdgcn_mfma_f32_16x16x32_f16(
                        vf[dt], pf[it][x], o[dt][it], 0, 0, 0);
        }
        __builtin_amdgcn_sched_barrier(0);
        __builtin_amdgcn_s_barrier();   // readers done -> next iter may restage
    }

    // epilogue: l per query col i (reduce over 4 lane-groups), divide, store
    float inv[2];
#pragma unroll
    for (int it = 0; it < 2; ++it) {
        float l = lp[it];
        l += __shfl_xor(l, 16);
        l += __shfl_xor(l, 32);
        inv[it] = __builtin_amdgcn_rcpf(l);
    }
#pragma unroll
    for (int dt = 0; dt < 4; ++dt)
#pragma unroll
        for (int it = 0; it < 2; ++it) {
            const int i = i0 + it * 16 + li;
            h4_t w = {(_Float16)(o[dt][it][0] * inv[it]),
                      (_Float16)(o[dt][it][1] * inv[it]),
                      (_Float16)(o[dt][it][2] * inv[it]),
                      (_Float16)(o[dt][it][3] * inv[it])};
            *(h4_t*)(O + (size_t)(bp * NTOK + i) * CDIM + h * DH + dt * 16 +
                     g * 4) = w;
        }
}

// ---------------------------------------------------------------------------
// ws layout (bytes):
//   [0, 32M)      XB  : LN'd input fp16 (reused per tensor, then attn out)
//   [32M, +2M)    WH  : Wq*0.125, Wk, Wv, Wo fp16
//   then QHp (32M), KHp (32M), VTg (32M, per-head transposed V)
// ---------------------------------------------------------------------------
extern "C" void kernel_launch(void* const* d_in, const int* in_sizes, int n_in,
                              void* d_out, int out_size, void* d_ws, size_t ws_size,
                              hipStream_t stream) {
    const float* q    = (const float*)d_in[0];
    const float* k    = (const float*)d_in[1];
    const float* v    = (const float*)d_in[2];
    const float* mask = (const float*)d_in[3];
    const float* pos  = (const float*)d_in[4];
    const float* lnqg = (const float*)d_in[5];
    const float* lnqb = (const float*)d_in[6];
    const float* lnkg = (const float*)d_in[7];
    const float* lnkb = (const float*)d_in[8];
    const float* lnvg = (const float*)d_in[9];
    const float* lnvb = (const float*)d_in[10];
    const float* Wq   = (const float*)d_in[11];
    const float* Wk   = (const float*)d_in[12];
    const float* Wv   = (const float*)d_in[13];
    const float* Wo   = (const float*)d_in[14];
    const float* bo   = (const float*)d_in[15];
    float* out = (float*)d_out;

    char* ws = (char*)d_ws;
    const size_t XSZ = (size_t)ROWS * CDIM * sizeof(_Float16);  // 33554432
    _Float16* XB  = (_Float16*)ws;
    _Float16* WH  = (_Float16*)(ws + XSZ);
    _Float16* QHp = (_Float16*)(ws + XSZ + 4 * (size_t)(CDIM * CDIM) * sizeof(_Float16));
    _Float16* KHp = QHp + (size_t)ROWS * CDIM;
    _Float16* VTg = KHp + (size_t)ROWS * CDIM;

    cast_w4<<<dim3(256, 4), 256, 0, stream>>>(Wq, Wk, Wv, Wo, WH);

    ln_cast<<<8192, 256, 0, stream>>>(q, lnqg, lnqb, XB);
    gemm_bt<0><<<1024, 256, 0, stream>>>(XB, WH + 0 * (CDIM * CDIM), QHp, nullptr, nullptr);
    ln_cast<<<8192, 256, 0, stream>>>(k, lnkg, lnkb, XB);
    gemm_bt<0><<<1024, 256, 0, stream>>>(XB, WH + 1 * (CDIM * CDIM), KHp, nullptr, nullptr);
    ln_cast<<<8192, 256, 0, stream>>>(v, lnvg, lnvb, XB);
    gemm_bt<2><<<1024, 256, 0, stream>>>(XB, WH + 2 * (CDIM * CDIM), VTg, nullptr, nullptr);

    attn_mfma<<<2048, 256, 0, stream>>>(QHp, KHp, VTg, mask, pos, XB);

    gemm_bt<1><<<1024, 256, 0, stream>>>(XB, WH + 3 * (CDIM * CDIM), nullptr, out, bo);
}

// Round 4
// 460.641 us; speedup vs baseline: 1.1812x; 1.1812x over previous
//
#include <hip/hip_runtime.h>
#include <hip/hip_fp16.h>

// Problem constants (B=2, P=64, N=256, C=512, H=8, D=64)
#define BP   128
#define NTOK 256
#define CDIM 512
#define ROWS 32768   // BP*NTOK
#define NH   8
#define DH   64

typedef _Float16 h2_t __attribute__((ext_vector_type(2)));
typedef _Float16 h4_t __attribute__((ext_vector_type(4)));
typedef _Float16 h8_t __attribute__((ext_vector_type(8)));
typedef float    f4_t __attribute__((ext_vector_type(4)));
typedef unsigned int u2v __attribute__((ext_vector_type(2)));

// pack two f32 -> two fp16 in one u32 (v_cvt_pkrtz_f16_f32)
__device__ __forceinline__ unsigned pkrtz(float a, float b) {
    return __builtin_bit_cast(unsigned, __builtin_amdgcn_cvt_pkrtz(a, b));
}

// async global->LDS, 16B per lane. LDS dest = wave-uniform base + lane*16.
__device__ __forceinline__ void async16(const void* gptr, void* lptr) {
    __builtin_amdgcn_global_load_lds(
        (const __attribute__((address_space(1))) unsigned int*)gptr,
        (__attribute__((address_space(3))) unsigned int*)lptr, 16, 0, 0);
}

// permlane32_swap: swaps lanes 32-63 of a with lanes 0-31 of b.
__device__ __forceinline__ u2v pl32swap(unsigned a, unsigned b) {
#if __has_builtin(__builtin_amdgcn_permlane32_swap)
    return __builtin_amdgcn_permlane32_swap(a, b, false, false);
#else
    const bool hi = (threadIdx.x & 32) != 0;
    unsigned sa = (unsigned)__shfl_xor((int)a, 32);
    unsigned sb = (unsigned)__shfl_xor((int)b, 32);
    u2v r; r[0] = hi ? sb : a; r[1] = hi ? b : sa; return r;
#endif
}

// permlane16_swap: swaps odd 16-lane rows of a with even rows of b.
__device__ __forceinline__ u2v pl16swap(unsigned a, unsigned b) {
#if __has_builtin(__builtin_amdgcn_permlane16_swap)
    return __builtin_amdgcn_permlane16_swap(a, b, false, false);
#else
    const bool odd = (threadIdx.x & 16) != 0;
    unsigned sa = (unsigned)__shfl_xor((int)a, 16);
    unsigned sb = (unsigned)__shfl_xor((int)b, 16);
    u2v r; r[0] = odd ? sb : a; r[1] = odd ? b : sa; return r;
#endif
}

// ---------------------------------------------------------------------------
// LayerNorm + cast to fp16. One wave per row of 512.
// ---------------------------------------------------------------------------
__global__ __launch_bounds__(256) void ln_cast(const float* __restrict__ x,
                                               const float* __restrict__ g,
                                               const float* __restrict__ b,
                                               _Float16* __restrict__ y) {
    const int wave = threadIdx.x >> 6, lane = threadIdx.x & 63;
    const size_t row = (size_t)blockIdx.x * 4 + wave;
    const float4* xr = (const float4*)(x + row * CDIM);
    float4 a0 = xr[2 * lane], a1 = xr[2 * lane + 1];
    float s  = a0.x + a0.y + a0.z + a0.w + a1.x + a1.y + a1.z + a1.w;
    float ss = a0.x * a0.x + a0.y * a0.y + a0.z * a0.z + a0.w * a0.w +
               a1.x * a1.x + a1.y * a1.y + a1.z * a1.z + a1.w * a1.w;
#pragma unroll
    for (int off = 32; off; off >>= 1) {
        s  += __shfl_xor(s, off);
        ss += __shfl_xor(ss, off);
    }
    const float mu = s * (1.f / 512.f);
    const float rs = rsqrtf(ss * (1.f / 512.f) - mu * mu + 1e-5f);
    const float4* gp = (const float4*)g;
    const float4* bpp = (const float4*)b;
    float4 g0 = gp[2 * lane], g1 = gp[2 * lane + 1];
    float4 b0 = bpp[2 * lane], b1 = bpp[2 * lane + 1];
    h8_t o;
    o[0] = (_Float16)((a0.x - mu) * rs * g0.x + b0.x);
    o[1] = (_Float16)((a0.y - mu) * rs * g0.y + b0.y);
    o[2] = (_Float16)((a0.z - mu) * rs * g0.z + b0.z);
    o[3] = (_Float16)((a0.w - mu) * rs * g0.w + b0.w);
    o[4] = (_Float16)((a1.x - mu) * rs * g1.x + b1.x);
    o[5] = (_Float16)((a1.y - mu) * rs * g1.y + b1.y);
    o[6] = (_Float16)((a1.z - mu) * rs * g1.z + b1.z);
    o[7] = (_Float16)((a1.w - mu) * rs * g1.w + b1.w);
    ((h8_t*)(y + row * CDIM))[lane] = o;
}

// ---------------------------------------------------------------------------
// Cast the 4 weight matrices (512x512 f32) to fp16. Wq gets *0.125 folded in.
// ---------------------------------------------------------------------------
__global__ __launch_bounds__(256) void cast_w4(const float* __restrict__ w0,
                                               const float* __restrict__ w1,
                                               const float* __restrict__ w2,
                                               const float* __restrict__ w3,
                                               _Float16* __restrict__ o) {
    const float* srcs[4] = {w0, w1, w2, w3};
    const float* w = srcs[blockIdx.y];
    const float scale = (blockIdx.y == 0) ? 0.125f : 1.0f;
    _Float16* dst = o + (size_t)blockIdx.y * (CDIM * CDIM);
    const int idx = blockIdx.x * 256 + threadIdx.x;  // 65536 float4 chunks
    float4 v = ((const float4*)w)[idx];
    h4_t ov = {(_Float16)(v.x * scale), (_Float16)(v.y * scale),
               (_Float16)(v.z * scale), (_Float16)(v.w * scale)};
    ((h4_t*)dst)[idx] = ov;
}

// ---------------------------------------------------------------------------
// GEMM (m97 structure): C[M=32768, 512] = A[32768,512] @ B^T.
// 1D grid (1024 blocks), XCD-chunked swizzle: xcd = bid&7 owns row-tiles
// [xcd*32, +32), iterating the 4 column tiles fastest so the same A row-panel
// hits that XCD's L2 4x (A fetched once from HBM instead of 4x).
// ---------------------------------------------------------------------------
template <int MODE>
__global__ __launch_bounds__(256) void gemm_bt(const _Float16* __restrict__ A,
                                               const _Float16* __restrict__ Bw,
                                               _Float16* __restrict__ Ch,
                                               float* __restrict__ Cf,
                                               const float* __restrict__ bias) {
    constexpr int K = CDIM;
    __shared__ __align__(16) _Float16 As[128 * 64];
    __shared__ __align__(16) _Float16 Bs[128 * 64];
    const int t = threadIdx.x;
    const int wave = t >> 6, lane = t & 63;
    const int wm = wave & 1, wn = wave >> 1;

    const int bid = blockIdx.x;          // 0..1023
    const int xcd = bid & 7, idx = bid >> 3;          // 128 per XCD
    const size_t rowBase = (size_t)(xcd * 32 + (idx >> 2)) * 128;
    const int colBase = (idx & 3) * 128;

    f4_t acc[4][4] = {};

    const int srow = t >> 3;
    const int scol = (t & 7) * 8;
    const _Float16* Ap = A + (rowBase + srow) * K + scol;
    const _Float16* Bp = Bw + ((size_t)colBase + srow) * K + scol;
    char* AsB = (char*)As + wave * 1024;
    char* BsB = (char*)Bs + wave * 1024;

    for (int k0 = 0; k0 < K; k0 += 64) {
#pragma unroll
        for (int c = 0; c < 4; ++c) {
            async16(Ap + (size_t)(32 * c) * K + k0, AsB + c * 4096);
            async16(Bp + (size_t)(32 * c) * K + k0, BsB + c * 4096);
        }
        __syncthreads();
#pragma unroll
        for (int kk = 0; kk < 64; kk += 32) {
            h8_t af[4], bf[4];
#pragma unroll
            for (int i = 0; i < 4; ++i)
                af[i] = *(const h8_t*)(As + (wm * 64 + i * 16 + (lane & 15)) * 64 +
                                       kk + (lane >> 4) * 8);
#pragma unroll
            for (int j = 0; j < 4; ++j)
                bf[j] = *(const h8_t*)(Bs + (wn * 64 + j * 16 + (lane & 15)) * 64 +
                                       kk + (lane >> 4) * 8);
#pragma unroll
            for (int i = 0; i < 4; ++i)
#pragma unroll
                for (int j = 0; j < 4; ++j)
                    acc[i][j] = __builtin_amdgcn_mfma_f32_16x16x32_f16(
                        af[i], bf[j], acc[i][j], 0, 0, 0);
        }
        __syncthreads();
    }
#pragma unroll
    for (int i = 0; i < 4; ++i) {
        const size_t growb = rowBase + wm * 64 + i * 16 + ((lane >> 4) * 4);
#pragma unroll
        for (int j = 0; j < 4; ++j) {
            const int gcol = colBase + wn * 64 + j * 16 + (lane & 15);
            if (MODE == 2) {
                const int bp = (int)(growb >> 8), tok = (int)(growb & 255);
                const int hh = gcol >> 6, dd = gcol & 63;
                h4_t w = {(_Float16)acc[i][j][0], (_Float16)acc[i][j][1],
                          (_Float16)acc[i][j][2], (_Float16)acc[i][j][3]};
                *(h4_t*)(Ch + ((size_t)(bp * NH + hh) * DH + dd) * NTOK + tok) = w;
            } else {
#pragma unroll
                for (int r = 0; r < 4; ++r) {
                    const size_t idx2 = (growb + r) * CDIM + gcol;
                    if (MODE == 0)
                        Ch[idx2] = (_Float16)acc[i][j][r];
                    else
                        Cf[idx2] = acc[i][j][r] + bias[gcol];
                }
            }
        }
    }
}

// ---------------------------------------------------------------------------
// MFMA flash attention, v4: same 2-phase double-buffered pipeline as v3, but
// __launch_bounds__(256, 2): v3's (256,4) made the allocator target 64 VGPR
// and spill ~270 MB of scratch per dispatch (WRITE_SIZE 299 MB vs 32 MB of O;
// dur == hbm_bytes/achieved-BW -> memory-bound on spill traffic). The live
// state (o 32 + s 32 + qf 16 + pf 16 + addr) wants ~110-130 VGPR; (256,2)
// lets it allocate spill-free (r0 precedent: 124 VGPR, clean 35 MB writes).
// ---------------------------------------------------------------------------
__global__ __launch_bounds__(256, 2) void attn_mfma(const _Float16* __restrict__ Q,
                                                    const _Float16* __restrict__ K,
                                                    const _Float16* __restrict__ VT,
                                                    const float* __restrict__ mask,
                                                    const float* __restrict__ pos,
                                                    _Float16* __restrict__ O) {
    const int bid = blockIdx.x;                   // 0..2047
    const int xcd = bid & 7, idx = bid >> 3;      // 256 per XCD
    const int bp = xcd + 8 * (idx >> 4);          // same-XCD blocks share bp
    const int sub = idx & 15;
    const int h = sub & 7, qh = sub >> 3;

    const int t = threadIdx.x;
    const int wave = t >> 6, lane = t & 63;
    const int g = lane >> 4, li = lane & 15;

    __shared__ __align__(16) _Float16 Ks[2][64 * 64];   // [j][d], slot-swizzled
    __shared__ __align__(16) _Float16 VTs[2][64 * 64];  // [d][j], slot-swizzled

    const int i0 = qh * 128 + wave * 32;

    // Q B-fragments, resident: qf[it][x]: rows i0+it*16+li, k = x*32+g*8..+8
    h8_t qf[2][2];
#pragma unroll
    for (int it = 0; it < 2; ++it)
#pragma unroll
        for (int x = 0; x < 2; ++x)
            qf[it][x] = *(const h8_t*)(Q +
                (size_t)(bp * NTOK + i0 + it * 16 + li) * CDIM +
                h * DH + x * 32 + g * 8);

    // staging: wave w covers LDS bytes [w*2048, +2048) in 2 calls of 1KB.
    // LDS byte = w*2048 + call*1024 + lane*16 -> row = w*16+call*8+(lane>>3),
    // slot = lane&7; source slot = (lane&7) ^ (row&7).
    const int srow = wave * 16 + (lane >> 3);
    const int sslot = (lane & 7) ^ ((lane >> 3) & 7);
    const _Float16* kSrc = K + ((size_t)(bp * NTOK) + srow) * CDIM + h * DH + sslot * 8;
    const _Float16* vSrc = VT + ((size_t)((bp * NH + h) * DH) + srow) * NTOK + sslot * 8;
    char* KsB[2] = {(char*)Ks[0] + wave * 2048, (char*)Ks[1] + wave * 2048};
    char* VsB[2] = {(char*)VTs[0] + wave * 2048, (char*)VTs[1] + wave * 2048};

    // swizzled read column offsets (fp16 elems): rows jt*16+li -> row&7 = li&7
    const int sw = li & 7;
    const int cx0 = (g ^ sw) * 8;        // x=0: slot g
    const int cx1 = ((4 + g) ^ sw) * 8;  // x=1: slot 4+g

    const float* mrow0 = mask + (size_t)bp * (NTOK * NTOK) + (size_t)(i0 + li) * NTOK + g * 4;
    const float* prow0 = pos + (size_t)h * (NTOK * NTOK) + (size_t)(i0 + li) * NTOK + g * 4;

    f4_t o[4][2] = {};   // O^T tiles [dt][it]
    float lp[2] = {0.f, 0.f};

    // prologue: stage chunk 0 into buf 0
    async16(kSrc, KsB[0]);
    async16(kSrc + 8 * CDIM, KsB[0] + 1024);
    async16(vSrc, VsB[0]);
    async16(vSrc + 8 * NTOK, VsB[0] + 1024);

#pragma unroll
    for (int c = 0; c < 4; ++c) {
        const int cur = c & 1;
        if (c < 3) {
            const int nb = cur ^ 1;
            async16(kSrc + (size_t)(c + 1) * 64 * CDIM, KsB[nb]);
            async16(kSrc + (size_t)(c + 1) * 64 * CDIM + 8 * CDIM, KsB[nb] + 1024);
            async16(vSrc + (c + 1) * 64, VsB[nb]);
            async16(vSrc + (c + 1) * 64 + 8 * NTOK, VsB[nb] + 1024);
            asm volatile("s_waitcnt vmcnt(4)" ::: "memory");
        } else {
            asm volatile("s_waitcnt vmcnt(0)" ::: "memory");
        }
        __builtin_amdgcn_s_barrier();
        __builtin_amdgcn_sched_barrier(0);

        const _Float16* Kc = Ks[cur];
        const _Float16* Vc = VTs[cur];

        // S^T = K Q^T
        f4_t s[4][2] = {};
#pragma unroll
        for (int x = 0; x < 2; ++x) {
            const int cc = x ? cx1 : cx0;
            h8_t kf[4];
#pragma unroll
            for (int jt = 0; jt < 4; ++jt)
                kf[jt] = *(const h8_t*)(Kc + (jt * 16 + li) * 64 + cc);
#pragma unroll
            for (int jt = 0; jt < 4; ++jt)
#pragma unroll
                for (int it = 0; it < 2; ++it)
                    s[jt][it] = __builtin_amdgcn_mfma_f32_16x16x32_f16(
                        kf[jt], qf[it][x], s[jt][it], 0, 0, 0);
        }

        // transform: p = exp(mask*(s + pos)); accumulate l; build B-fragments
        // in-register (cvt_pkrtz + permlane swaps), no LDS round-trip.
        h8_t pf[2][2];
#pragma unroll
        for (int it = 0; it < 2; ++it) {
            const float* mr = mrow0 + it * (16 * NTOK) + c * 64;
            const float* pr = prow0 + it * (16 * NTOK) + c * 64;
            unsigned pk[4][2];
#pragma unroll
            for (int jt = 0; jt < 4; ++jt) {
                float4 mm = *(const float4*)(mr + jt * 16);
                float4 pp = *(const float4*)(pr + jt * 16);
                float e0 = __expf((s[jt][it][0] + pp.x) * mm.x);
                float e1 = __expf((s[jt][it][1] + pp.y) * mm.y);
                float e2 = __expf((s[jt][it][2] + pp.z) * mm.z);
                float e3 = __expf((s[jt][it][3] + pp.w) * mm.w);
                lp[it] += (e0 + e1) + (e2 + e3);
                pk[jt][0] = pkrtz(e0, e1);  // rows (4g, 4g+1)
                pk[jt][1] = pkrtz(e2, e3);  // rows (4g+2, 4g+3)
            }
#pragma unroll
            for (int x = 0; x < 2; ++x) {
                u2v r0 = pl32swap(pk[2 * x][0], pk[2 * x + 1][0]);
                u2v r1 = pl32swap(pk[2 * x][1], pk[2 * x + 1][1]);
                u2v q0 = pl16swap(r0[0], r0[1]);
                u2v q1 = pl16swap(r1[0], r1[1]);
                union { unsigned u[4]; h8_t v; } u;
                u.u[0] = q0[0]; u.u[1] = q1[0]; u.u[2] = q0[1]; u.u[3] = q1[1];
                pf[it][x] = u.v;
            }
        }

        // O^T += V^T P^T
#pragma unroll
        for (int x = 0; x < 2; ++x) {
            const int cc = x ? cx1 : cx0;
            h8_t vf[4];
#pragma unroll
            for (int dt = 0; dt < 4; ++dt)
                vf[dt] = *(const h8_t*)(Vc + (dt * 16 + li) * 64 + cc);
#pragma unroll
            for (int dt = 0; dt < 4; ++dt)
#pragma unroll
                for (int it = 0; it < 2; ++it)
                    o[dt][it] = __builtin_amdgcn_mfma_f32_16x16x32_f16(
                        vf[dt], pf[it][x], o[dt][it], 0, 0, 0);
        }
        __builtin_amdgcn_sched_barrier(0);
        __builtin_amdgcn_s_barrier();   // readers done -> next iter may restage
    }

    // epilogue: l per query col i (reduce over 4 lane-groups), divide, store
    float inv[2];
#pragma unroll
    for (int it = 0; it < 2; ++it) {
        float l = lp[it];
        l += __shfl_xor(l, 16);
        l += __shfl_xor(l, 32);
        inv[it] = __builtin_amdgcn_rcpf(l);
    }
#pragma unroll
    for (int dt = 0; dt < 4; ++dt)
#pragma unroll
        for (int it = 0; it < 2; ++it) {
            const int i = i0 + it * 16 + li;
            h4_t w = {(_Float16)(o[dt][it][0] * inv[it]),
                      (_Float16)(o[dt][it][1] * inv[it]),
                      (_Float16)(o[dt][it][2] * inv[it]),
                      (_Float16)(o[dt][it][3] * inv[it])};
            *(h4_t*)(O + (size_t)(bp * NTOK + i) * CDIM + h * DH + dt * 16 +
                     g * 4) = w;
        }
}

// ---------------------------------------------------------------------------
// ws layout (bytes):
//   [0, 32M)      XB  : LN'd input fp16 (reused per tensor, then attn out)
//   [32M, +2M)    WH  : Wq*0.125, Wk, Wv, Wo fp16
//   then QHp (32M), KHp (32M), VTg (32M, per-head transposed V)
// ---------------------------------------------------------------------------
extern "C" void kernel_launch(void* const* d_in, const int* in_sizes, int n_in,
                              void* d_out, int out_size, void* d_ws, size_t ws_size,
                              hipStream_t stream) {
    const float* q    = (const float*)d_in[0];
    const float* k    = (const float*)d_in[1];
    const float* v    = (const float*)d_in[2];
    const float* mask = (const float*)d_in[3];
    const float* pos  = (const float*)d_in[4];
    const float* lnqg = (const float*)d_in[5];
    const float* lnqb = (const float*)d_in[6];
    const float* lnkg = (const float*)d_in[7];
    const float* lnkb = (const float*)d_in[8];
    const float* lnvg = (const float*)d_in[9];
    const float* lnvb = (const float*)d_in[10];
    const float* Wq   = (const float*)d_in[11];
    const float* Wk   = (const float*)d_in[12];
    const float* Wv   = (const float*)d_in[13];
    const float* Wo   = (const float*)d_in[14];
    const float* bo   = (const float*)d_in[15];
    float* out = (float*)d_out;

    char* ws = (char*)d_ws;
    const size_t XSZ = (size_t)ROWS * CDIM * sizeof(_Float16);  // 33554432
    _Float16* XB  = (_Float16*)ws;
    _Float16* WH  = (_Float16*)(ws + XSZ);
    _Float16* QHp = (_Float16*)(ws + XSZ + 4 * (size_t)(CDIM * CDIM) * sizeof(_Float16));
    _Float16* KHp = QHp + (size_t)ROWS * CDIM;
    _Float16* VTg = KHp + (size_t)ROWS * CDIM;

    cast_w4<<<dim3(256, 4), 256, 0, stream>>>(Wq, Wk, Wv, Wo, WH);

    ln_cast<<<8192, 256, 0, stream>>>(q, lnqg, lnqb, XB);
    gemm_bt<0><<<1024, 256, 0, stream>>>(XB, WH + 0 * (CDIM * CDIM), QHp, nullptr, nullptr);
    ln_cast<<<8192, 256, 0, stream>>>(k, lnkg, lnkb, XB);
    gemm_bt<0><<<1024, 256, 0, stream>>>(XB, WH + 1 * (CDIM * CDIM), KHp, nullptr, nullptr);
    ln_cast<<<8192, 256, 0, stream>>>(v, lnvg, lnvb, XB);
    gemm_bt<2><<<1024, 256, 0, stream>>>(XB, WH + 2 * (CDIM * CDIM), VTg, nullptr, nullptr);

    attn_mfma<<<2048, 256, 0, stream>>>(QHp, KHp, VTg, mask, pos, XB);

    gemm_bt<1><<<1024, 256, 0, stream>>>(XB, WH + 3 * (CDIM * CDIM), nullptr, out, bo);
}